// Round 14
// baseline (726.244 us; speedup 1.0000x reference)
//
#include <hip/hip_runtime.h>
#include <stdint.h>

// LSTM step: B=4096, IN=1024, H=4096. bf16-MFMA GEMMs with fp32 accumulate.
// GEMM = 256x256 tile, BK=64, 8 waves, 8-phase/2-K-tile pipeline with ONE
// barrier per phase (round-12 champion main loop, byte-identical), counted
// vmcnt (T3+T4), LDS XOR-swizzle (T2), setprio (T5), XCD swizzle (T1),
// LDS round-trip epilogue (coalesced 512B-row stores).
// NEW (launch-level only): all 5 conversions in ONE launch, all 4 gate-GEMMs
// in ONE 1024-block launch (gate = blockIdx>>8, uniform pointer select) ->
// no inter-launch drains, A panel stays L3-resident across gates.
// Needs 328 MiB ws (A + 4 Wb + 4 P); falls back to round-12 sequence.
#define IN_ 1024
#define H_  4096
#define B_  4096
#define K_  5120   // IN_ + H_ (K-concat of x|hidden and Wx|Wh)
#define NT_ 80     // K_ / 64 K-tiles

typedef short bf16x8 __attribute__((ext_vector_type(8)));
typedef float f32x4  __attribute__((ext_vector_type(4)));

__device__ __forceinline__ unsigned short f2bf(float x) {
    union { float f; uint32_t u; } v; v.f = x;
    return (unsigned short)((v.u + 0x7FFFu + ((v.u >> 16) & 1u)) >> 16);  // RNE
}
__device__ __forceinline__ float bf2f(uint32_t u16) {
    union { uint32_t u; float f; } v; v.u = u16 << 16; return v.f;
}

// Convert up to 5 independent (s1[r][1024] | s2[r][4096]) -> bf16 [r][5120]
// concat jobs in one launch. Job u covers blocks [u*20480, (u+1)*20480).
__global__ __launch_bounds__(256) void cvt_cat5(
    const float* __restrict__ a1, const float* __restrict__ a2, unsigned short* __restrict__ ad,
    const float* __restrict__ b1, const float* __restrict__ b2, unsigned short* __restrict__ bd,
    const float* __restrict__ c1, const float* __restrict__ c2, unsigned short* __restrict__ cd,
    const float* __restrict__ d1, const float* __restrict__ d2, unsigned short* __restrict__ dd,
    const float* __restrict__ e1, const float* __restrict__ e2, unsigned short* __restrict__ ed)
{
    const int unit = blockIdx.x / 20480;          // uniform
    const int sub  = blockIdx.x - unit * 20480;
    const float* s1 = (unit == 0) ? a1 : (unit == 1) ? b1 : (unit == 2) ? c1 : (unit == 3) ? d1 : e1;
    const float* s2 = (unit == 0) ? a2 : (unit == 1) ? b2 : (unit == 2) ? c2 : (unit == 3) ? d2 : e2;
    unsigned short* dst = (unit == 0) ? ad : (unit == 1) ? bd : (unit == 2) ? cd : (unit == 3) ? dd : ed;

    int idx = sub * 256 + threadIdx.x;            // one float4 per thread
    int r = idx / (K_ / 4);
    int c = (idx % (K_ / 4)) * 4;
    float4 v;
    if (c < IN_) v = *(const float4*)(s1 + (size_t)r * IN_ + c);
    else         v = *(const float4*)(s2 + (size_t)r * H_ + (c - IN_));
    ushort4 o = { f2bf(v.x), f2bf(v.y), f2bf(v.z), f2bf(v.w) };
    *(ushort4*)(dst + (size_t)r * K_ + c) = o;
}

// LDS swizzle: within a [256][32]-bf16 sub-tile (64 B rows), XOR byte-col
// bits 4-5 with row bits 1-2. Measured conflict-free for 16-row fragment
// reads (rounds 2-12: SQ_LDS_BANK_CONFLICT = 0 in main loop).
__device__ __forceinline__ int swz(int row) { return ((row >> 1) & 3) << 4; }

// NT GEMM: P[m][n] = bf16( sum_k A[m][k]*W[n][k] + bias[n] )
// gate = blockIdx>>8 selects {W,bias,P} (uniform, top-level); blocks within a
// gate use the proven XCD-bijective swizzle (256 = 0 mod 8 keeps it exact).
__global__ __launch_bounds__(512, 2) void gemm_gate8(
    const unsigned short* __restrict__ A,
    const unsigned short* __restrict__ W0, const unsigned short* __restrict__ W1,
    const unsigned short* __restrict__ W2, const unsigned short* __restrict__ W3,
    const float* __restrict__ bias0, const float* __restrict__ bias1,
    const float* __restrict__ bias2, const float* __restrict__ bias3,
    unsigned short* __restrict__ P0, unsigned short* __restrict__ P1,
    unsigned short* __restrict__ P2, unsigned short* __restrict__ P3)
{
    const int gate = blockIdx.x >> 8;             // uniform
    const unsigned short* W = (gate == 0) ? W0 : (gate == 1) ? W1 : (gate == 2) ? W2 : W3;
    const float* bias = (gate == 0) ? bias0 : (gate == 1) ? bias1 : (gate == 2) ? bias2 : bias3;
    unsigned short* P = (gate == 0) ? P0 : (gate == 1) ? P1 : (gate == 2) ? P2 : P3;

    // ---- GEMM body: byte-identical to round-12 champion ----
    // 128 KiB: buf(2) x { A_k0 | A_k1 | B_k0 | B_k1 }, each [256][32] bf16 (16 KiB)
    __shared__ __align__(16) char ldsb[131072];

    const int tid  = threadIdx.x;
    const int wid  = tid >> 6;
    const int lane = tid & 63;

    // XCD-bijective block swizzle within the gate's 256 blocks.
    const int b8 = blockIdx.x & 255;
    const int wg = (b8 & 7) * 32 + (b8 >> 3);
    const int mt = wg & 15, nt = wg >> 4;
    const int bm = mt * 256, bn = nt * 256;

    const int wm = wid >> 2;   // 0..1 -> wave M-half (128 rows)
    const int wn = wid & 3;    // 0..3 -> wave N-quarter (64 cols)

    const int l15 = lane & 15;
    const int c0  = (lane >> 4) << 4;   // fragment k-slot byte offset (0/16/32/48)

    // staging coords: thread owns 16B slots q0 = wid*64+lane and q0+512 of each
    // 16 KiB sub-tile; LDS write is linear, global SOURCE column pre-swizzled.
    const int q0  = wid * 64 + lane;
    const int r0  = q0 >> 2;                       // row 0..127
    const int cb0 = ((q0 & 3) << 4) ^ swz(r0);     // logical col byte
    const int r1  = r0 + 128;                      // row 128..255 (slot q0+512)
    const int cb1 = ((q0 & 3) << 4) ^ swz(r1);

    f32x4 acc[8][4];
#pragma unroll
    for (int i = 0; i < 8; ++i)
#pragma unroll
        for (int j = 0; j < 4; ++j) acc[i][j] = (f32x4){0.f, 0.f, 0.f, 0.f};

    // stage one sub-tile (2 x global_load_lds width-16 per thread)
    auto stage = [&](int isB, int ksel, int tau) {
        if (tau >= NT_) tau = NT_ - 2 + (tau & 1);  // tail clamp, parity-preserving
        const int kbase = tau * 64 + ksel * 32;
        const int chunk = (tau & 1) * 65536 + isB * 32768 + ksel * 16384;
        const unsigned short* src = isB ? W : A;
        const int gb = isB ? bn : bm;
        __builtin_amdgcn_global_load_lds(
            (const __attribute__((address_space(1))) void*)(src + (size_t)(gb + r0) * K_ + kbase + (cb0 >> 1)),
            (__attribute__((address_space(3))) void*)(ldsb + chunk + wid * 1024), 16, 0, 0);
        __builtin_amdgcn_global_load_lds(
            (const __attribute__((address_space(1))) void*)(src + (size_t)(gb + r1) * K_ + kbase + (cb1 >> 1)),
            (__attribute__((address_space(3))) void*)(ldsb + chunk + 8192 + wid * 1024), 16, 0, 0);
    };

    // prologue: buf0 <- tile0 (A+B), buf1.B <- tile1.
    // vmcnt(4): tile0's 8 loads landed; buf1.B pair (4 loads) may stay in flight.
    stage(0, 0, 0); stage(0, 1, 0); stage(1, 0, 0); stage(1, 1, 0);
    stage(1, 0, 1); stage(1, 1, 1);
    asm volatile("s_waitcnt vmcnt(4)" ::: "memory");
    __builtin_amdgcn_s_barrier();

    for (int i = 0; i < NT_ / 2; ++i) {
        const int T0 = 2 * i;
        bf16x8 b[2][4];     // B fragments, refreshed at phases 0 and 4
#pragma unroll
        for (int k = 0; k < 8; ++k) {
            const int half = k >> 2;            // buf index (T0 even)
            const int q    = k & 3;             // C-quadrant
            const char* Abase = ldsb + half * 65536;
            const char* Bbase = Abase + 32768;

            // [R] reads, kh0 group first so the compiler's counted lgkm wait
            // lets MFMA-kh0 start while kh1 reads are still in flight.
            bf16x8 a0[2], a1[2];
            if (q == 0) {
#pragma unroll
                for (int ni = 0; ni < 4; ++ni) {
                    const int row = wn * 64 + ni * 16 + l15;
                    b[0][ni] = *(const bf16x8*)(Bbase + row * 64 + (c0 ^ swz(row)));
                }
            }
#pragma unroll
            for (int mi = 0; mi < 2; ++mi) {
                const int row = wm * 128 + q * 32 + mi * 16 + l15;
                a0[mi] = *(const bf16x8*)(Abase + row * 64 + (c0 ^ swz(row)));
            }
            if (q == 0) {
#pragma unroll
                for (int ni = 0; ni < 4; ++ni) {
                    const int row = wn * 64 + ni * 16 + l15;
                    b[1][ni] = *(const bf16x8*)(Bbase + 16384 + row * 64 + (c0 ^ swz(row)));
                }
            }
#pragma unroll
            for (int mi = 0; mi < 2; ++mi) {
                const int row = wm * 128 + q * 32 + mi * 16 + l15;
                a1[mi] = *(const bf16x8*)(Abase + 16384 + row * 64 + (c0 ^ swz(row)));
            }

            // [V] collective landing guarantee for the NEXT 4 phases' reads.
            if (q == 3) asm volatile("s_waitcnt vmcnt(2)" ::: "memory");
            // [BAR] one barrier per phase
            __builtin_amdgcn_s_barrier();

            // [S] stage exactly 1 sub-tile per phase (dead-slot ledger):
            //  ph0: buf1.A_k0<-T0+1  ph1: buf1.A_k1<-T0+1  (buf1.A last read ph7 prev)
            //  ph2: buf0.B_k0<-T0+2  ph3: buf0.B_k1<-T0+2  (buf0.B last read ph0)
            //  ph4: buf0.A_k0<-T0+2  ph5: buf0.A_k1<-T0+2  (buf0.A last read ph3)
            //  ph6: buf1.B_k0<-T0+3  ph7: buf1.B_k1<-T0+3  (buf1.B last read ph4)
            if      (k == 0) stage(0, 0, T0 + 1);
            else if (k == 1) stage(0, 1, T0 + 1);
            else if (k == 2) stage(1, 0, T0 + 2);
            else if (k == 3) stage(1, 1, T0 + 2);
            else if (k == 4) stage(0, 0, T0 + 2);
            else if (k == 5) stage(0, 1, T0 + 2);
            else if (k == 6) stage(1, 0, T0 + 3);
            else             stage(1, 1, T0 + 3);
            __builtin_amdgcn_sched_barrier(0);   // pin MFMA below barrier+stage

            __builtin_amdgcn_s_setprio(1);
#pragma unroll
            for (int mi = 0; mi < 2; ++mi)        // kh0 cluster (8 MFMA)
#pragma unroll
                for (int ni = 0; ni < 4; ++ni)
                    acc[q * 2 + mi][ni] = __builtin_amdgcn_mfma_f32_16x16x32_bf16(
                        a0[mi], b[0][ni], acc[q * 2 + mi][ni], 0, 0, 0);
#pragma unroll
            for (int mi = 0; mi < 2; ++mi)        // kh1 cluster (8 MFMA)
#pragma unroll
                for (int ni = 0; ni < 4; ++ni)
                    acc[q * 2 + mi][ni] = __builtin_amdgcn_mfma_f32_16x16x32_bf16(
                        a1[mi], b[1][ni], acc[q * 2 + mi][ni], 0, 0, 0);
            __builtin_amdgcn_s_setprio(0);
        }
    }

    // ---- epilogue: LDS round-trip for coalesced P writes (branch-free) ----
    asm volatile("s_waitcnt vmcnt(0)" ::: "memory");
    __builtin_amdgcn_s_barrier();

    // bf16 tile [256 rows][512 B], 16B-slot XOR on row bits to spread banks.
    // C/D layout: col=lane&15, row=(lane>>4)*4+reg  [m89-verified]
#pragma unroll
    for (int ni = 0; ni < 4; ++ni) {
        const int col = wn * 64 + ni * 16 + l15;           // local col 0..255
        const float bv = bias[bn + col];
#pragma unroll
        for (int mi = 0; mi < 8; ++mi) {
            const int rowb = wm * 128 + mi * 16 + (lane >> 4) * 4;
#pragma unroll
            for (int r = 0; r < 4; ++r) {
                const int row  = rowb + r;
                const int byte = row * 512 + ((col * 2) ^ ((row & 7) << 4));
                *(unsigned short*)(ldsb + byte) = f2bf(acc[mi][ni][r] + bv);
            }
        }
    }
    __builtin_amdgcn_s_barrier();

    // coalesced store: 16 iters x (ds_read_b128 + global_store_dwordx4);
    // each half-wave covers one full 512B row (32 x 16B chunks).
#pragma unroll
    for (int c = 0; c < 16; ++c) {
        const int idx = c * 512 + tid;
        const int row = idx >> 5;                          // 0..255
        const int cb  = (idx & 31) * 16;                   // 16B chunk byte-col
        bf16x8 v = *(const bf16x8*)(ldsb + row * 512 + (cb ^ ((row & 7) << 4)));
        *(bf16x8*)&P[(size_t)(bm + row) * H_ + bn + cb / 2] = v;
    }
}

// Fused gate elementwise + output GEMV. One block per batch row.
__global__ __launch_bounds__(256) void gates_gemv(
    const unsigned short* __restrict__ Pi, const unsigned short* __restrict__ Pf,
    const unsigned short* __restrict__ Po, const unsigned short* __restrict__ Pc,
    const float* __restrict__ cell, const float* __restrict__ Wy,
    const float* __restrict__ by, float* __restrict__ y)
{
    const int b = blockIdx.x;
    const int t = threadIdx.x;
    const size_t base = (size_t)b * H_;
    float part = 0.f;

#pragma unroll
    for (int j = 0; j < 4; ++j) {
        const int h = j * 1024 + t * 4;
        const uint2 ri = *(const uint2*)(Pi + base + h);
        const uint2 rf = *(const uint2*)(Pf + base + h);
        const uint2 ro = *(const uint2*)(Po + base + h);
        const uint2 rc = *(const uint2*)(Pc + base + h);
        const float4 cv = *(const float4*)(cell + base + h);
        const float4 wv = *(const float4*)(Wy + h);

        const uint32_t zi[4] = { ri.x & 0xffffu, ri.x >> 16, ri.y & 0xffffu, ri.y >> 16 };
        const uint32_t zf[4] = { rf.x & 0xffffu, rf.x >> 16, rf.y & 0xffffu, rf.y >> 16 };
        const uint32_t zo[4] = { ro.x & 0xffffu, ro.x >> 16, ro.y & 0xffffu, ro.y >> 16 };
        const uint32_t zc[4] = { rc.x & 0xffffu, rc.x >> 16, rc.y & 0xffffu, rc.y >> 16 };
        const float cc[4] = { cv.x, cv.y, cv.z, cv.w };
        const float ww[4] = { wv.x, wv.y, wv.z, wv.w };
#pragma unroll
        for (int e = 0; e < 4; ++e) {
            const float ig = 1.f / (1.f + __expf(-bf2f(zi[e])));
            const float fg = 1.f / (1.f + __expf(-bf2f(zf[e])));
            const float og = 1.f / (1.f + __expf(-bf2f(zo[e])));
            const float ct = tanhf(bf2f(zc[e]));
            const float cn = fg * cc[e] + ig * ct;
            const float hn = og * tanhf(cn);
            part += hn * ww[e];
        }
    }

    // block reduce (deterministic, no atomics)
#pragma unroll
    for (int off = 32; off > 0; off >>= 1) part += __shfl_down(part, off, 64);
    __shared__ float red[4];
    if ((t & 63) == 0) red[t >> 6] = part;
    __syncthreads();
    if (t == 0) y[b] = red[0] + red[1] + red[2] + red[3] + by[0];
}

extern "C" void kernel_launch(void* const* d_in, const int* in_sizes, int n_in,
                              void* d_out, int out_size, void* d_ws, size_t ws_size,
                              hipStream_t stream) {
    const float* x      = (const float*)d_in[0];
    const float* hidden = (const float*)d_in[1];
    const float* cell   = (const float*)d_in[2];
    const float* Wx[4]  = { (const float*)d_in[3], (const float*)d_in[4],
                            (const float*)d_in[5], (const float*)d_in[6] };
    const float* bx[4]  = { (const float*)d_in[7], (const float*)d_in[8],
                            (const float*)d_in[9], (const float*)d_in[10] };
    const float* Wh[4]  = { (const float*)d_in[11], (const float*)d_in[12],
                            (const float*)d_in[13], (const float*)d_in[14] };
    const float* Wy     = (const float*)d_in[15];
    const float* by     = (const float*)d_in[16];
    float* y = (float*)d_out;

    const int cvt_grid = (B_ * (K_ / 4)) / 256;   // 20480 blocks per job
    const size_t WKE = (size_t)H_ * K_;           // 20,971,520 elems (40 MiB bf16)
    const size_t PKE = (size_t)B_ * H_;           // 16,777,216 elems (32 MiB bf16)
    const size_t need = (WKE * 5 + PKE * 4) * sizeof(unsigned short);  // 328 MiB

    if (ws_size >= need) {
        // ws: Ab | Wb0..Wb3 | P0..P3
        unsigned short* Ab = (unsigned short*)d_ws;
        unsigned short* Wb[4];
        for (int g = 0; g < 4; ++g) Wb[g] = Ab + WKE * (1 + g);
        unsigned short* Pg[4];
        for (int g = 0; g < 4; ++g) Pg[g] = Ab + WKE * 5 + (size_t)g * PKE;

        // one launch: A + all 4 W conversions (no inter-launch drains)
        cvt_cat5<<<5 * cvt_grid, 256, 0, stream>>>(
            x, hidden, Ab,
            Wx[0], Wh[0], Wb[0], Wx[1], Wh[1], Wb[1],
            Wx[2], Wh[2], Wb[2], Wx[3], Wh[3], Wb[3]);

        // one launch: all 4 gate GEMMs (CUs backfill across gates; A stays L3-hot)
        gemm_gate8<<<1024, 512, 0, stream>>>(
            Ab, Wb[0], Wb[1], Wb[2], Wb[3],
            bx[0], bx[1], bx[2], bx[3],
            Pg[0], Pg[1], Pg[2], Pg[3]);

        gates_gemv<<<B_, 256, 0, stream>>>(Pg[0], Pg[1], Pg[2], Pg[3], cell, Wy, by, y);
    } else {
        // fallback: round-12 sequence (208 MiB)
        unsigned short* Ab = (unsigned short*)d_ws;
        unsigned short* Wb = Ab + WKE;
        unsigned short* Pg[4];
        for (int g = 0; g < 4; ++g) Pg[g] = Wb + WKE + (size_t)g * PKE;

        cvt_cat5<<<cvt_grid, 256, 0, stream>>>(
            x, hidden, Ab,
            nullptr, nullptr, nullptr, nullptr, nullptr, nullptr,
            nullptr, nullptr, nullptr, nullptr, nullptr, nullptr);
        for (int g = 0; g < 4; ++g) {
            cvt_cat5<<<cvt_grid, 256, 0, stream>>>(
                Wx[g], Wh[g], Wb,
                nullptr, nullptr, nullptr, nullptr, nullptr, nullptr,
                nullptr, nullptr, nullptr, nullptr, nullptr, nullptr);
            gemm_gate8<<<256, 512, 0, stream>>>(
                Ab, Wb, Wb, Wb, Wb,
                bx[g], bx[g], bx[g], bx[g],
                Pg[g], Pg[g], Pg[g], Pg[g]);
        }
        gates_gemv<<<B_, 256, 0, stream>>>(Pg[0], Pg[1], Pg[2], Pg[3], cell, Wy, by, y);
    }
}

// Round 15
// 673.519 us; speedup vs baseline: 1.0783x; 1.0783x over previous
//
#include <hip/hip_runtime.h>
#include <stdint.h>

// LSTM step: B=4096, IN=1024, H=4096. bf16-MFMA GEMMs with fp32 accumulate.
// GEMM = 256x256 tile, BK=64, 8 waves, 8-phase/2-K-tile pipeline with ONE
// barrier per phase. Round-15: phases regrouped by (kh, q-pair) so LDS reads
// per phase are [8,4,8,4] instead of [12,4,4,4] — flattens the phase-0 LDS
// burst that serialized against the MFMA cluster. Stage schedule, vmcnt
// points, and ledger identical to the round-12 champion.
// Counted vmcnt (T3+T4), LDS XOR-swizzle (T2), setprio (T5), XCD swizzle (T1),
// LDS round-trip epilogue (coalesced 512B-row stores).
#define IN_ 1024
#define H_  4096
#define B_  4096
#define K_  5120   // IN_ + H_ (K-concat of x|hidden and Wx|Wh)
#define NT_ 80     // K_ / 64 K-tiles

typedef short bf16x8 __attribute__((ext_vector_type(8)));
typedef float f32x4  __attribute__((ext_vector_type(4)));

__device__ __forceinline__ unsigned short f2bf(float x) {
    union { float f; uint32_t u; } v; v.f = x;
    return (unsigned short)((v.u + 0x7FFFu + ((v.u >> 16) & 1u)) >> 16);  // RNE
}
__device__ __forceinline__ float bf2f(uint32_t u16) {
    union { uint32_t u; float f; } v; v.u = u16 << 16; return v.f;
}

// Build bf16 [rows][5120] = concat(s1 [rows][1024], s2 [rows][4096]), RNE.
__global__ __launch_bounds__(256) void cvt_cat(
    const float* __restrict__ s1, const float* __restrict__ s2,
    unsigned short* __restrict__ dst)
{
    int idx = blockIdx.x * 256 + threadIdx.x;       // one float4 per thread
    int r = idx / (K_ / 4);
    int c = (idx % (K_ / 4)) * 4;
    float4 v;
    if (c < IN_) v = *(const float4*)(s1 + (size_t)r * IN_ + c);
    else         v = *(const float4*)(s2 + (size_t)r * H_ + (c - IN_));
    ushort4 o = { f2bf(v.x), f2bf(v.y), f2bf(v.z), f2bf(v.w) };
    *(ushort4*)(dst + (size_t)r * K_ + c) = o;
}

// LDS swizzle: within a [256][32]-bf16 sub-tile (64 B rows), XOR byte-col
// bits 4-5 with row bits 1-2. Measured conflict-free for 16-row fragment
// reads (rounds 2-14: SQ_LDS_BANK_CONFLICT = 0 in main loop).
__device__ __forceinline__ int swz(int row) { return ((row >> 1) & 3) << 4; }

// NT GEMM: P[m][n] = bf16( sum_k A[m][k]*W[n][k] + bias[n] )
__global__ __launch_bounds__(512, 2) void gemm_gate8(
    const unsigned short* __restrict__ A,
    const unsigned short* __restrict__ W,
    const float* __restrict__ bias,
    unsigned short* __restrict__ P)
{
    // 128 KiB: buf(2) x { A_k0 | A_k1 | B_k0 | B_k1 }, each [256][32] bf16 (16 KiB)
    __shared__ __align__(16) char ldsb[131072];

    const int tid  = threadIdx.x;
    const int wid  = tid >> 6;
    const int lane = tid & 63;

    // XCD-bijective block swizzle: 256 blocks, 8 XCDs, 32 blocks/XCD chunk.
    const int wg = (blockIdx.x & 7) * 32 + (blockIdx.x >> 3);
    const int mt = wg & 15, nt = wg >> 4;
    const int bm = mt * 256, bn = nt * 256;

    const int wm = wid >> 2;   // 0..1 -> wave M-half (128 rows)
    const int wn = wid & 3;    // 0..3 -> wave N-quarter (64 cols)

    const int l15 = lane & 15;
    const int c0  = (lane >> 4) << 4;   // fragment k-slot byte offset (0/16/32/48)

    // staging coords: thread owns 16B slots q0 = wid*64+lane and q0+512 of each
    // 16 KiB sub-tile; LDS write is linear, global SOURCE column pre-swizzled.
    const int q0  = wid * 64 + lane;
    const int r0  = q0 >> 2;                       // row 0..127
    const int cb0 = ((q0 & 3) << 4) ^ swz(r0);     // logical col byte
    const int r1  = r0 + 128;                      // row 128..255 (slot q0+512)
    const int cb1 = ((q0 & 3) << 4) ^ swz(r1);

    f32x4 acc[8][4];
#pragma unroll
    for (int i = 0; i < 8; ++i)
#pragma unroll
        for (int j = 0; j < 4; ++j) acc[i][j] = (f32x4){0.f, 0.f, 0.f, 0.f};

    // stage one sub-tile (2 x global_load_lds width-16 per thread)
    auto stage = [&](int isB, int ksel, int tau) {
        if (tau >= NT_) tau = NT_ - 2 + (tau & 1);  // tail clamp, parity-preserving
        const int kbase = tau * 64 + ksel * 32;
        const int chunk = (tau & 1) * 65536 + isB * 32768 + ksel * 16384;
        const unsigned short* src = isB ? W : A;
        const int gb = isB ? bn : bm;
        __builtin_amdgcn_global_load_lds(
            (const __attribute__((address_space(1))) void*)(src + (size_t)(gb + r0) * K_ + kbase + (cb0 >> 1)),
            (__attribute__((address_space(3))) void*)(ldsb + chunk + wid * 1024), 16, 0, 0);
        __builtin_amdgcn_global_load_lds(
            (const __attribute__((address_space(1))) void*)(src + (size_t)(gb + r1) * K_ + kbase + (cb1 >> 1)),
            (__attribute__((address_space(3))) void*)(ldsb + chunk + 8192 + wid * 1024), 16, 0, 0);
    };

    // prologue: buf0 <- tile0 (A+B), buf1.B <- tile1.
    // vmcnt(4): tile0's 8 loads landed; buf1.B pair (4 loads) may stay in flight.
    stage(0, 0, 0); stage(0, 1, 0); stage(1, 0, 0); stage(1, 1, 0);
    stage(1, 0, 1); stage(1, 1, 1);
    asm volatile("s_waitcnt vmcnt(4)" ::: "memory");
    __builtin_amdgcn_s_barrier();

    for (int i = 0; i < NT_ / 2; ++i) {
        const int T0 = 2 * i;
        bf16x8 b[4];        // B fragments for the CURRENT kh (refreshed pp 0/2)
#pragma unroll
        for (int k = 0; k < 8; ++k) {
            const int half = k >> 2;            // buf index (T0 even)
            const int pp   = k & 3;             // phase within half-window
            const int kh   = pp >> 1;           // k-half this phase computes
            const int qp   = pp & 1;            // quadrant pair (q = 2*qp, 2*qp+1)
            const char* Abase = ldsb + half * 65536 + kh * 16384;
            const char* Bbase = ldsb + half * 65536 + 32768 + kh * 16384;

            // [R] reads: b[kh] only when kh changes (pp 0/2: 4 reads); a-frags
            // for this phase's 2 quadrants (4 reads). Max 8 reads/phase.
            bf16x8 a[2][2];                     // [quadrant-in-pair][mi]
            if (qp == 0) {
#pragma unroll
                for (int ni = 0; ni < 4; ++ni) {
                    const int row = wn * 64 + ni * 16 + l15;
                    b[ni] = *(const bf16x8*)(Bbase + row * 64 + (c0 ^ swz(row)));
                }
            }
#pragma unroll
            for (int j = 0; j < 2; ++j)
#pragma unroll
                for (int mi = 0; mi < 2; ++mi) {
                    const int row = wm * 128 + (qp * 2 + j) * 32 + mi * 16 + l15;
                    a[j][mi] = *(const bf16x8*)(Abase + row * 64 + (c0 ^ swz(row)));
                }

            // [V] collective landing guarantee for the NEXT 4 phases' reads.
            if (pp == 3) asm volatile("s_waitcnt vmcnt(2)" ::: "memory");
            // [BAR] one barrier per phase
            __builtin_amdgcn_s_barrier();

            // [S] stage exactly 1 sub-tile per phase (identical schedule to
            // round-12; ledger re-verified under the new read placement):
            //  ph0: buf1.A_k0<-T0+1  ph1: buf1.A_k1<-T0+1
            //  ph2: buf0.B_k0<-T0+2  ph3: buf0.B_k1<-T0+2
            //  ph4: buf0.A_k0<-T0+2  ph5: buf0.A_k1<-T0+2
            //  ph6: buf1.B_k0<-T0+3  ph7: buf1.B_k1<-T0+3
            if      (k == 0) stage(0, 0, T0 + 1);
            else if (k == 1) stage(0, 1, T0 + 1);
            else if (k == 2) stage(1, 0, T0 + 2);
            else if (k == 3) stage(1, 1, T0 + 2);
            else if (k == 4) stage(0, 0, T0 + 2);
            else if (k == 5) stage(0, 1, T0 + 2);
            else if (k == 6) stage(1, 0, T0 + 3);
            else             stage(1, 1, T0 + 3);
            __builtin_amdgcn_sched_barrier(0);   // pin MFMA below barrier+stage

            __builtin_amdgcn_s_setprio(1);
#pragma unroll
            for (int j = 0; j < 2; ++j)           // 16 MFMA: 2 quadrants x 2 mi x 4 ni
#pragma unroll
                for (int mi = 0; mi < 2; ++mi)
#pragma unroll
                    for (int ni = 0; ni < 4; ++ni)
                        acc[(qp * 2 + j) * 2 + mi][ni] =
                            __builtin_amdgcn_mfma_f32_16x16x32_bf16(
                                a[j][mi], b[ni], acc[(qp * 2 + j) * 2 + mi][ni], 0, 0, 0);
            __builtin_amdgcn_s_setprio(0);
        }
    }

    // ---- epilogue: LDS round-trip for coalesced P writes (branch-free) ----
    asm volatile("s_waitcnt vmcnt(0)" ::: "memory");
    __builtin_amdgcn_s_barrier();

    // bf16 tile [256 rows][512 B], 16B-slot XOR on row bits to spread banks.
    // C/D layout: col=lane&15, row=(lane>>4)*4+reg  [m89-verified]
#pragma unroll
    for (int ni = 0; ni < 4; ++ni) {
        const int col = wn * 64 + ni * 16 + l15;           // local col 0..255
        const float bv = bias[bn + col];
#pragma unroll
        for (int mi = 0; mi < 8; ++mi) {
            const int rowb = wm * 128 + mi * 16 + (lane >> 4) * 4;
#pragma unroll
            for (int r = 0; r < 4; ++r) {
                const int row  = rowb + r;
                const int byte = row * 512 + ((col * 2) ^ ((row & 7) << 4));
                *(unsigned short*)(ldsb + byte) = f2bf(acc[mi][ni][r] + bv);
            }
        }
    }
    __builtin_amdgcn_s_barrier();

    // coalesced store: 16 iters x (ds_read_b128 + global_store_dwordx4);
    // each half-wave covers one full 512B row (32 x 16B chunks).
#pragma unroll
    for (int c = 0; c < 16; ++c) {
        const int idx = c * 512 + tid;
        const int row = idx >> 5;                          // 0..255
        const int cb  = (idx & 31) * 16;                   // 16B chunk byte-col
        bf16x8 v = *(const bf16x8*)(ldsb + row * 512 + (cb ^ ((row & 7) << 4)));
        *(bf16x8*)&P[(size_t)(bm + row) * H_ + bn + cb / 2] = v;
    }
}

// Fused gate elementwise + output GEMV. One block per batch row.
__global__ __launch_bounds__(256) void gates_gemv(
    const unsigned short* __restrict__ Pi, const unsigned short* __restrict__ Pf,
    const unsigned short* __restrict__ Po, const unsigned short* __restrict__ Pc,
    const float* __restrict__ cell, const float* __restrict__ Wy,
    const float* __restrict__ by, float* __restrict__ y)
{
    const int b = blockIdx.x;
    const int t = threadIdx.x;
    const size_t base = (size_t)b * H_;
    float part = 0.f;

#pragma unroll
    for (int j = 0; j < 4; ++j) {
        const int h = j * 1024 + t * 4;
        const uint2 ri = *(const uint2*)(Pi + base + h);
        const uint2 rf = *(const uint2*)(Pf + base + h);
        const uint2 ro = *(const uint2*)(Po + base + h);
        const uint2 rc = *(const uint2*)(Pc + base + h);
        const float4 cv = *(const float4*)(cell + base + h);
        const float4 wv = *(const float4*)(Wy + h);

        const uint32_t zi[4] = { ri.x & 0xffffu, ri.x >> 16, ri.y & 0xffffu, ri.y >> 16 };
        const uint32_t zf[4] = { rf.x & 0xffffu, rf.x >> 16, rf.y & 0xffffu, rf.y >> 16 };
        const uint32_t zo[4] = { ro.x & 0xffffu, ro.x >> 16, ro.y & 0xffffu, ro.y >> 16 };
        const uint32_t zc[4] = { rc.x & 0xffffu, rc.x >> 16, rc.y & 0xffffu, rc.y >> 16 };
        const float cc[4] = { cv.x, cv.y, cv.z, cv.w };
        const float ww[4] = { wv.x, wv.y, wv.z, wv.w };
#pragma unroll
        for (int e = 0; e < 4; ++e) {
            const float ig = 1.f / (1.f + __expf(-bf2f(zi[e])));
            const float fg = 1.f / (1.f + __expf(-bf2f(zf[e])));
            const float og = 1.f / (1.f + __expf(-bf2f(zo[e])));
            const float ct = tanhf(bf2f(zc[e]));
            const float cn = fg * cc[e] + ig * ct;
            const float hn = og * tanhf(cn);
            part += hn * ww[e];
        }
    }

    // block reduce (deterministic, no atomics)
#pragma unroll
    for (int off = 32; off > 0; off >>= 1) part += __shfl_down(part, off, 64);
    __shared__ float red[4];
    if ((t & 63) == 0) red[t >> 6] = part;
    __syncthreads();
    if (t == 0) y[b] = red[0] + red[1] + red[2] + red[3] + by[0];
}

extern "C" void kernel_launch(void* const* d_in, const int* in_sizes, int n_in,
                              void* d_out, int out_size, void* d_ws, size_t ws_size,
                              hipStream_t stream) {
    const float* x      = (const float*)d_in[0];
    const float* hidden = (const float*)d_in[1];
    const float* cell   = (const float*)d_in[2];
    const float* Wx[4]  = { (const float*)d_in[3], (const float*)d_in[4],
                            (const float*)d_in[5], (const float*)d_in[6] };
    const float* bx[4]  = { (const float*)d_in[7], (const float*)d_in[8],
                            (const float*)d_in[9], (const float*)d_in[10] };
    const float* Wh[4]  = { (const float*)d_in[11], (const float*)d_in[12],
                            (const float*)d_in[13], (const float*)d_in[14] };
    const float* Wy     = (const float*)d_in[15];
    const float* by     = (const float*)d_in[16];
    float* y = (float*)d_out;

    // ws layout (~208 MiB), round-12 champion sequence:
    //   A  bf16 [4096][5120]   : 40 MiB
    //   Wb bf16 [4096][5120]   : 40 MiB (reused per gate; stream-serialized)
    //   P  bf16 [4][4096][4096]: 128 MiB
    unsigned short* Ab = (unsigned short*)d_ws;
    unsigned short* Wb = Ab + (size_t)B_ * K_;
    unsigned short* Pg[4];
    {
        unsigned short* p0 = Wb + (size_t)H_ * K_;
        for (int g = 0; g < 4; ++g) Pg[g] = p0 + (size_t)g * B_ * H_;
    }

    const int cvt_grid = (B_ * (K_ / 4)) / 256;   // 20480, exact
    cvt_cat<<<cvt_grid, 256, 0, stream>>>(x, hidden, Ab);

    for (int g = 0; g < 4; ++g) {
        cvt_cat<<<cvt_grid, 256, 0, stream>>>(Wx[g], Wh[g], Wb);
        gemm_gate8<<<256, 512, 0, stream>>>(Ab, Wb, bx[g], Pg[g]);
    }

    gates_gemv<<<B_, 256, 0, stream>>>(Pg[0], Pg[1], Pg[2], Pg[3], cell, Wy, by, y);
}